// Round 3
// baseline (450.549 us; speedup 1.0000x reference)
//
#include <hip/hip_runtime.h>

typedef short bf16x8 __attribute__((ext_vector_type(8)));
typedef float f32x4 __attribute__((ext_vector_type(4)));

__device__ __forceinline__ unsigned short f2bf(float f) {
    unsigned u = __float_as_uint(f);
    unsigned r = (u + 0x7fffu + ((u >> 16) & 1u)) >> 16;
    return (unsigned short)r;
}

// ---------------- CSR build ----------------
__global__ void k_initdeg(int* deg, int N) {
    int i = blockIdx.x * blockDim.x + threadIdx.x;
    if (i < N) deg[i] = 1;  // self-loop
}
__global__ void k_hist(const int* __restrict__ ei, int E, int* deg) {
    int e = blockIdx.x * blockDim.x + threadIdx.x;
    if (e < E) atomicAdd(&deg[ei[E + e]], 1);
}
__global__ void k_scan(const int* __restrict__ deg, int* __restrict__ off,
                       int* __restrict__ cur, int N) {
    __shared__ int sums[1024];
    int t = threadIdx.x;
    int chunk = (N + 1023) >> 10;
    int lo = t * chunk;
    int hi = lo + chunk; if (hi > N) hi = N;
    if (lo > N) lo = N;
    int s = 0;
    for (int i = lo; i < hi; ++i) s += deg[i];
    sums[t] = s;
    __syncthreads();
    for (int dd = 1; dd < 1024; dd <<= 1) {
        int v = (t >= dd) ? sums[t - dd] : 0;
        __syncthreads();
        sums[t] += v;
        __syncthreads();
    }
    int run = sums[t] - s;  // exclusive prefix
    for (int i = lo; i < hi; ++i) { off[i] = run; cur[i] = run; run += deg[i]; }
    if (t == 1023) off[N] = run;
}
__global__ void k_fill(const int* __restrict__ ei, int E, int N,
                       int* cur, int* __restrict__ csr) {
    int i = blockIdx.x * blockDim.x + threadIdx.x;
    if (i < E) {
        int s = ei[i], d = ei[E + i];
        int pos = atomicAdd(&cur[d], 1);
        csr[pos] = s;
    } else if (i < E + N) {
        int nn = i - E;
        int pos = atomicAdd(&cur[nn], 1);
        csr[pos] = nn;
    }
}
// transpose f32 W[K,Nc] -> bf16 WT[Nc,K]
__global__ void k_transpose(const float* __restrict__ W,
                            unsigned short* __restrict__ WT, int K, int Nc) {
    int i = blockIdx.x * blockDim.x + threadIdx.x;
    if (i < K * Nc) {
        int k = i / Nc, n = i - k * Nc;
        WT[n * K + k] = f2bf(W[i]);
    }
}
// elementwise f32 -> bf16
__global__ void k_cvt(const float* __restrict__ in, unsigned short* __restrict__ out, int n) {
    int i = blockIdx.x * blockDim.x + threadIdx.x;
    if (i < n) out[i] = f2bf(in[i]);
}

// ---------------- GEMM: D[M,Nc] (f32) = A[M,K] (bf16) @ BT[Nc,K]^T (bf16) ----
// one wave computes a 64x64 tile with 4x4 mfma_f32_16x16x32_bf16 accumulators
__global__ __launch_bounds__(256) void k_gemm(
    const unsigned short* __restrict__ A, const unsigned short* __restrict__ BT,
    float* __restrict__ D, int M, int K, int Nc, int tiles_n)
{
    int wid = blockIdx.x * (blockDim.x >> 6) + (threadIdx.x >> 6);
    int tiles_m = (M + 63) >> 6;
    if (wid >= tiles_m * tiles_n) return;
    int lane = threadIdx.x & 63;
    int tm = wid / tiles_n, tn = wid - tm * tiles_n;
    int m0 = tm << 6, n0 = tn << 6;
    int r = lane & 15, q = lane >> 4;
    f32x4 acc[4][4] = {};
    for (int k0 = 0; k0 < K; k0 += 32) {
        int ka = k0 + q * 8;
        bf16x8 a[4], b[4];
#pragma unroll
        for (int i = 0; i < 4; ++i) {
            int row = m0 + 16 * i + r; row = row < M ? row : M - 1;
            a[i] = *(const bf16x8*)(A + (size_t)row * K + ka);
        }
#pragma unroll
        for (int j = 0; j < 4; ++j) {
            int col = n0 + 16 * j + r;
            b[j] = *(const bf16x8*)(BT + (size_t)col * K + ka);
        }
#pragma unroll
        for (int i = 0; i < 4; ++i)
#pragma unroll
            for (int j = 0; j < 4; ++j)
                acc[i][j] = __builtin_amdgcn_mfma_f32_16x16x32_bf16(a[i], b[j], acc[i][j], 0, 0, 0);
    }
#pragma unroll
    for (int i = 0; i < 4; ++i) {
        int rowb = m0 + 16 * i + q * 4;
#pragma unroll
        for (int rr = 0; rr < 4; ++rr) {
            int row = rowb + rr;
            if (row < M) {
#pragma unroll
                for (int j = 0; j < 4; ++j) {
                    int col = n0 + 16 * j + r;
                    D[(size_t)row * Nc + col] = acc[i][j][rr];
                }
            }
        }
    }
}

// ---------------- attention logits per node: al_s, al_d -------------------
template <int HCt, int Ht>
__global__ __launch_bounds__(256) void k_al(
    const float* __restrict__ h, const float* __restrict__ asrc,
    const float* __restrict__ adst,
    float* __restrict__ als, float* __restrict__ ald, int N)
{
    int wid = blockIdx.x * (blockDim.x >> 6) + (threadIdx.x >> 6);
    if (wid >= N) return;
    int lane = threadIdx.x & 63;
    const int CH = HCt / 64;
    const int Gs = 64 / Ht;  // lanes per head
    const float* hr = h + (size_t)wid * HCt + lane * CH;
    float s = 0.f, d = 0.f;
#pragma unroll
    for (int j = 0; j < CH; ++j) {
        float hv = hr[j];
        int ch = lane * CH + j;
        s += hv * asrc[ch];
        d += hv * adst[ch];
    }
#pragma unroll
    for (int dd = 1; dd < Gs; dd <<= 1) {
        s += __shfl_xor(s, dd);
        d += __shfl_xor(d, dd);
    }
    if ((lane & (Gs - 1)) == 0) {
        int hh = lane / Gs;
        als[wid * Ht + hh] = s;
        ald[wid * Ht + hh] = d;
    }
}

// ---------------- softmax over in-edges + aggregate -----------------------
// one wave per dst node; lane owns CH contiguous channels
template <int HCt, int Ht, bool DOELU, bool OUTBF>
__global__ __launch_bounds__(256) void k_aggr(
    const float* __restrict__ h, const float* __restrict__ als,
    const float* __restrict__ aldv, const int* __restrict__ off,
    const int* __restrict__ csr, const float* __restrict__ bias,
    void* __restrict__ outp, int N)
{
    int n = blockIdx.x * (blockDim.x >> 6) + (threadIdx.x >> 6);
    if (n >= N) return;
    int lane = threadIdx.x & 63;
    const int CH = HCt / 64;
    const int C = HCt / Ht;
    int s0 = off[n], s1 = off[n + 1];

    float ald[Ht];
#pragma unroll
    for (int hh = 0; hh < Ht; ++hh) ald[hh] = aldv[n * Ht + hh];

    // pass 1: per-head max over in-edges (lane-parallel over edges)
    float mx[Ht];
#pragma unroll
    for (int hh = 0; hh < Ht; ++hh) mx[hh] = -3.4e38f;
    for (int t = s0 + lane; t < s1; t += 64) {
        int src = csr[t];
#pragma unroll
        for (int hh = 0; hh < Ht; ++hh) {
            float l = als[src * Ht + hh] + ald[hh];
            l = l > 0.f ? l : 0.2f * l;
            mx[hh] = fmaxf(mx[hh], l);
        }
    }
#pragma unroll
    for (int dd = 1; dd < 64; dd <<= 1)
#pragma unroll
        for (int hh = 0; hh < Ht; ++hh)
            mx[hh] = fmaxf(mx[hh], __shfl_xor(mx[hh], dd));

    int myhead = (lane * CH) / C;
    float mh = mx[0], aldh = ald[0];
#pragma unroll
    for (int hh = 1; hh < Ht; ++hh)
        if (hh == myhead) { mh = mx[hh]; aldh = ald[hh]; }

    // pass 2: exp-weighted accumulate (edges sequential, channels lane-parallel)
    float acc[CH];
#pragma unroll
    for (int j = 0; j < CH; ++j) acc[j] = 0.f;
    float den = 0.f;
    const float* hbase = h + lane * CH;
    for (int t = s0; t < s1; ++t) {
        int src = csr[t];
        float l = als[src * Ht + myhead] + aldh;
        l = l > 0.f ? l : 0.2f * l;
        float ex = __expf(l - mh);
        den += ex;
        const float* hr = hbase + (size_t)src * HCt;
        if constexpr (CH >= 4) {
            const f32x4* hr4 = (const f32x4*)hr;
#pragma unroll
            for (int v4 = 0; v4 < CH / 4; ++v4) {
                f32x4 hv = hr4[v4];
#pragma unroll
                for (int j = 0; j < 4; ++j) acc[v4 * 4 + j] += ex * hv[j];
            }
        } else {
#pragma unroll
            for (int j = 0; j < CH; ++j) acc[j] += ex * hr[j];
        }
    }
    float inv = 1.f / den;  // identical across lanes of one head
    int chb = lane * CH;
#pragma unroll
    for (int j = 0; j < CH; ++j) {
        float v = acc[j] * inv + bias[chb + j];
        if (DOELU) v = v > 0.f ? v : expm1f(v);
        if (OUTBF)
            ((unsigned short*)outp)[(size_t)n * HCt + chb + j] = f2bf(v);
        else
            ((float*)outp)[(size_t)n * HCt + chb + j] = v;
    }
}

// --------------------------------------------------------------------------
extern "C" void kernel_launch(void* const* d_in, const int* in_sizes, int n_in,
                              void* d_out, int out_size, void* d_ws, size_t ws_size,
                              hipStream_t stream)
{
    const float* x   = (const float*)d_in[0];
    const int*   ei  = (const int*)d_in[1];
    const float* W1  = (const float*)d_in[2];
    const float* as1 = (const float*)d_in[3];
    const float* ad1 = (const float*)d_in[4];
    const float* b1  = (const float*)d_in[5];
    const float* W2  = (const float*)d_in[6];
    const float* as2 = (const float*)d_in[7];
    const float* ad2 = (const float*)d_in[8];
    const float* b2  = (const float*)d_in[9];
    const float* W3  = (const float*)d_in[10];
    const float* as3 = (const float*)d_in[11];
    const float* ad3 = (const float*)d_in[12];
    const float* b3  = (const float*)d_in[13];

    const int DIN = 256, HC = 512, DOUT = 64;
    int N = in_sizes[0] / DIN;
    int E = in_sizes[1] / 2;

    // workspace carve-up
    char* w = (char*)d_ws;
    auto alloc = [&](size_t bytes) -> char* {
        char* p = w;
        w += (bytes + 255) & ~(size_t)255;
        return p;
    };
    int* deg   = (int*)alloc((size_t)N * 4);
    int* cur   = (int*)alloc((size_t)N * 4);
    int* off   = (int*)alloc((size_t)(N + 1) * 4);
    int* csr   = (int*)alloc((size_t)(E + N) * 4);
    unsigned short* W1T = (unsigned short*)alloc((size_t)HC * DIN * 2);
    unsigned short* W2T = (unsigned short*)alloc((size_t)HC * HC * 2);
    unsigned short* W3T = (unsigned short*)alloc((size_t)DOUT * HC * 2);
    unsigned short* xb  = (unsigned short*)alloc((size_t)N * DIN * 2);  // bf16 GEMM A (layer1)
    unsigned short* act = (unsigned short*)alloc((size_t)N * HC * 2);   // bf16 GEMM A (layer2/3)
    float* hbuf = (float*)alloc((size_t)N * HC * 4);
    float* als  = (float*)alloc((size_t)N * 4 * 4);
    float* ald  = (float*)alloc((size_t)N * 4 * 4);

    // ---- CSR build ----
    k_initdeg<<<(N + 255) / 256, 256, 0, stream>>>(deg, N);
    k_hist<<<(E + 255) / 256, 256, 0, stream>>>(ei, E, deg);
    k_scan<<<1, 1024, 0, stream>>>(deg, off, cur, N);
    k_fill<<<(E + N + 255) / 256, 256, 0, stream>>>(ei, E, N, cur, csr);

    // ---- weight transposes + input conversion ----
    k_transpose<<<(DIN * HC + 255) / 256, 256, 0, stream>>>(W1, W1T, DIN, HC);
    k_transpose<<<(HC * HC + 255) / 256, 256, 0, stream>>>(W2, W2T, HC, HC);
    k_transpose<<<(HC * DOUT + 255) / 256, 256, 0, stream>>>(W3, W3T, HC, DOUT);
    k_cvt<<<(N * DIN + 255) / 256, 256, 0, stream>>>(x, xb, N * DIN);

    int tiles_m = (N + 63) / 64;
    auto gemm_blocks = [&](int tn) { return (tiles_m * tn + 3) / 4; };
    int nwave_blocks = (N + 3) / 4;

    // ---- layer 1 ----
    k_gemm<<<gemm_blocks(HC / 64), 256, 0, stream>>>(xb, W1T, hbuf, N, DIN, HC, HC / 64);
    k_al<512, 4><<<nwave_blocks, 256, 0, stream>>>(hbuf, as1, ad1, als, ald, N);
    k_aggr<512, 4, true, true><<<nwave_blocks, 256, 0, stream>>>(hbuf, als, ald, off, csr, b1, act, N);

    // ---- layer 2 ----
    k_gemm<<<gemm_blocks(HC / 64), 256, 0, stream>>>(act, W2T, hbuf, N, HC, HC, HC / 64);
    k_al<512, 4><<<nwave_blocks, 256, 0, stream>>>(hbuf, as2, ad2, als, ald, N);
    k_aggr<512, 4, true, true><<<nwave_blocks, 256, 0, stream>>>(hbuf, als, ald, off, csr, b2, act, N);

    // ---- layer 3 ----
    k_gemm<<<gemm_blocks(1), 256, 0, stream>>>(act, W3T, hbuf, N, HC, DOUT, 1);
    k_al<64, 1><<<nwave_blocks, 256, 0, stream>>>(hbuf, as3, ad3, als, ald, N);
    k_aggr<64, 1, false, false><<<nwave_blocks, 256, 0, stream>>>(
        hbuf, als, ald, off, csr, b3, d_out, N);
}

// Round 4
// 388.387 us; speedup vs baseline: 1.1601x; 1.1601x over previous
//
#include <hip/hip_runtime.h>

typedef short bf16x8 __attribute__((ext_vector_type(8)));
typedef float f32x4 __attribute__((ext_vector_type(4)));

__device__ __forceinline__ unsigned short f2bf(float f) {
    unsigned u = __float_as_uint(f);
    unsigned r = (u + 0x7fffu + ((u >> 16) & 1u)) >> 16;
    return (unsigned short)r;
}
__device__ __forceinline__ float bfu2f(unsigned short u) {
    return __uint_as_float(((unsigned)u) << 16);
}

// ---------------- CSR build ----------------
__global__ void k_initdeg(int* deg, int N) {
    int i = blockIdx.x * blockDim.x + threadIdx.x;
    if (i < N) deg[i] = 1;  // self-loop
}
__global__ void k_hist(const int* __restrict__ ei, int E, int* deg) {
    int e = blockIdx.x * blockDim.x + threadIdx.x;
    if (e < E) atomicAdd(&deg[ei[E + e]], 1);
}
__global__ void k_scan(const int* __restrict__ deg, int* __restrict__ off,
                       int* __restrict__ cur, int N) {
    __shared__ int sums[1024];
    int t = threadIdx.x;
    int chunk = (N + 1023) >> 10;
    int lo = t * chunk;
    int hi = lo + chunk; if (hi > N) hi = N;
    if (lo > N) lo = N;
    int s = 0;
    for (int i = lo; i < hi; ++i) s += deg[i];
    sums[t] = s;
    __syncthreads();
    for (int dd = 1; dd < 1024; dd <<= 1) {
        int v = (t >= dd) ? sums[t - dd] : 0;
        __syncthreads();
        sums[t] += v;
        __syncthreads();
    }
    int run = sums[t] - s;  // exclusive prefix
    for (int i = lo; i < hi; ++i) { off[i] = run; cur[i] = run; run += deg[i]; }
    if (t == 1023) off[N] = run;
}
__global__ void k_fill(const int* __restrict__ ei, int E, int N,
                       int* cur, int* __restrict__ csr) {
    int i = blockIdx.x * blockDim.x + threadIdx.x;
    if (i < E) {
        int s = ei[i], d = ei[E + i];
        int pos = atomicAdd(&cur[d], 1);
        csr[pos] = s;
    } else if (i < E + N) {
        int nn = i - E;
        int pos = atomicAdd(&cur[nn], 1);
        csr[pos] = nn;
    }
}
// transpose f32 W[K,Nc] -> bf16 WT[Nc,K]
__global__ void k_transpose(const float* __restrict__ W,
                            unsigned short* __restrict__ WT, int K, int Nc) {
    int i = blockIdx.x * blockDim.x + threadIdx.x;
    if (i < K * Nc) {
        int k = i / Nc, n = i - k * Nc;
        WT[n * K + k] = f2bf(W[i]);
    }
}
// elementwise f32 -> bf16
__global__ void k_cvt(const float* __restrict__ in, unsigned short* __restrict__ out, int n) {
    int i = blockIdx.x * blockDim.x + threadIdx.x;
    if (i < n) out[i] = f2bf(in[i]);
}

// ---------------- GEMM: D[M,Nc] = A[M,K] (bf16) @ BT[Nc,K]^T (bf16) ----
// one wave computes a 64x64 tile with 4x4 mfma_f32_16x16x32_bf16 accumulators
// OUTBF: store bf16, else f32
template <bool OUTBF>
__global__ __launch_bounds__(256) void k_gemm(
    const unsigned short* __restrict__ A, const unsigned short* __restrict__ BT,
    void* __restrict__ D, int M, int K, int Nc, int tiles_n)
{
    int wid = blockIdx.x * (blockDim.x >> 6) + (threadIdx.x >> 6);
    int tiles_m = (M + 63) >> 6;
    if (wid >= tiles_m * tiles_n) return;
    int lane = threadIdx.x & 63;
    int tm = wid / tiles_n, tn = wid - tm * tiles_n;
    int m0 = tm << 6, n0 = tn << 6;
    int r = lane & 15, q = lane >> 4;
    f32x4 acc[4][4] = {};
    for (int k0 = 0; k0 < K; k0 += 32) {
        int ka = k0 + q * 8;
        bf16x8 a[4], b[4];
#pragma unroll
        for (int i = 0; i < 4; ++i) {
            int row = m0 + 16 * i + r; row = row < M ? row : M - 1;
            a[i] = *(const bf16x8*)(A + (size_t)row * K + ka);
        }
#pragma unroll
        for (int j = 0; j < 4; ++j) {
            int col = n0 + 16 * j + r;
            b[j] = *(const bf16x8*)(BT + (size_t)col * K + ka);
        }
#pragma unroll
        for (int i = 0; i < 4; ++i)
#pragma unroll
            for (int j = 0; j < 4; ++j)
                acc[i][j] = __builtin_amdgcn_mfma_f32_16x16x32_bf16(a[i], b[j], acc[i][j], 0, 0, 0);
    }
#pragma unroll
    for (int i = 0; i < 4; ++i) {
        int rowb = m0 + 16 * i + q * 4;
#pragma unroll
        for (int rr = 0; rr < 4; ++rr) {
            int row = rowb + rr;
            if (row < M) {
#pragma unroll
                for (int j = 0; j < 4; ++j) {
                    int col = n0 + 16 * j + r;
                    if (OUTBF)
                        ((unsigned short*)D)[(size_t)row * Nc + col] = f2bf(acc[i][j][rr]);
                    else
                        ((float*)D)[(size_t)row * Nc + col] = acc[i][j][rr];
                }
            }
        }
    }
}

// ---------------- attention logits per node: al_s, al_d -------------------
template <int HCt, int Ht, bool INBF>
__global__ __launch_bounds__(256) void k_al(
    const void* __restrict__ h, const float* __restrict__ asrc,
    const float* __restrict__ adst,
    float* __restrict__ als, float* __restrict__ ald, int N)
{
    int wid = blockIdx.x * (blockDim.x >> 6) + (threadIdx.x >> 6);
    if (wid >= N) return;
    int lane = threadIdx.x & 63;
    const int CH = HCt / 64;
    const int Gs = 64 / Ht;  // lanes per head
    float s = 0.f, d = 0.f;
    if constexpr (INBF) {
        const unsigned short* hr = (const unsigned short*)h + (size_t)wid * HCt + lane * CH;
#pragma unroll
        for (int j = 0; j < CH; ++j) {
            float hv = bfu2f(hr[j]);
            int ch = lane * CH + j;
            s += hv * asrc[ch];
            d += hv * adst[ch];
        }
    } else {
        const float* hr = (const float*)h + (size_t)wid * HCt + lane * CH;
#pragma unroll
        for (int j = 0; j < CH; ++j) {
            float hv = hr[j];
            int ch = lane * CH + j;
            s += hv * asrc[ch];
            d += hv * adst[ch];
        }
    }
#pragma unroll
    for (int dd = 1; dd < Gs; dd <<= 1) {
        s += __shfl_xor(s, dd);
        d += __shfl_xor(d, dd);
    }
    if ((lane & (Gs - 1)) == 0) {
        int hh = lane / Gs;
        als[wid * Ht + hh] = s;
        ald[wid * Ht + hh] = d;
    }
}

// ---------------- softmax over in-edges + aggregate -----------------------
// one wave per dst node; lane owns CH contiguous channels
template <int HCt, int Ht, bool DOELU, bool OUTBF, bool INBF>
__global__ __launch_bounds__(256) void k_aggr(
    const void* __restrict__ h, const float* __restrict__ als,
    const float* __restrict__ aldv, const int* __restrict__ off,
    const int* __restrict__ csr, const float* __restrict__ bias,
    void* __restrict__ outp, int N)
{
    int n = blockIdx.x * (blockDim.x >> 6) + (threadIdx.x >> 6);
    if (n >= N) return;
    int lane = threadIdx.x & 63;
    const int CH = HCt / 64;
    const int C = HCt / Ht;
    int s0 = off[n], s1 = off[n + 1];

    float ald[Ht];
#pragma unroll
    for (int hh = 0; hh < Ht; ++hh) ald[hh] = aldv[n * Ht + hh];

    // pass 1: per-head max over in-edges (lane-parallel over edges)
    float mx[Ht];
#pragma unroll
    for (int hh = 0; hh < Ht; ++hh) mx[hh] = -3.4e38f;
    for (int t = s0 + lane; t < s1; t += 64) {
        int src = csr[t];
#pragma unroll
        for (int hh = 0; hh < Ht; ++hh) {
            float l = als[src * Ht + hh] + ald[hh];
            l = l > 0.f ? l : 0.2f * l;
            mx[hh] = fmaxf(mx[hh], l);
        }
    }
#pragma unroll
    for (int dd = 1; dd < 64; dd <<= 1)
#pragma unroll
        for (int hh = 0; hh < Ht; ++hh)
            mx[hh] = fmaxf(mx[hh], __shfl_xor(mx[hh], dd));

    int myhead = (lane * CH) / C;
    float mh = mx[0], aldh = ald[0];
#pragma unroll
    for (int hh = 1; hh < Ht; ++hh)
        if (hh == myhead) { mh = mx[hh]; aldh = ald[hh]; }

    // pass 2: exp-weighted accumulate (edges sequential, channels lane-parallel)
    float acc[CH];
#pragma unroll
    for (int j = 0; j < CH; ++j) acc[j] = 0.f;
    float den = 0.f;
    for (int t = s0; t < s1; ++t) {
        int src = csr[t];
        float l = als[src * Ht + myhead] + aldh;
        l = l > 0.f ? l : 0.2f * l;
        float ex = __expf(l - mh);
        den += ex;
        if constexpr (INBF) {
            // CH == 8: one 16B load of 8 bf16 per lane
            const uint4* hr4 = (const uint4*)((const unsigned short*)h + (size_t)src * HCt) + lane;
            uint4 hv = *hr4;
            unsigned wds[4] = {hv.x, hv.y, hv.z, hv.w};
#pragma unroll
            for (int wv = 0; wv < 4; ++wv) {
                float lo = __uint_as_float(wds[wv] << 16);
                float hi = __uint_as_float(wds[wv] & 0xffff0000u);
                acc[wv * 2 + 0] += ex * lo;
                acc[wv * 2 + 1] += ex * hi;
            }
        } else if constexpr (CH >= 4) {
            const f32x4* hr4 = (const f32x4*)((const float*)h + (size_t)src * HCt) + lane * (CH / 4);
#pragma unroll
            for (int v4 = 0; v4 < CH / 4; ++v4) {
                f32x4 hv = hr4[v4];
#pragma unroll
                for (int j = 0; j < 4; ++j) acc[v4 * 4 + j] += ex * hv[j];
            }
        } else {
            const float* hr = (const float*)h + (size_t)src * HCt + lane * CH;
#pragma unroll
            for (int j = 0; j < CH; ++j) acc[j] += ex * hr[j];
        }
    }
    float inv = 1.f / den;  // identical across lanes of one head
    int chb = lane * CH;
#pragma unroll
    for (int j = 0; j < CH; ++j) {
        float v = acc[j] * inv + bias[chb + j];
        if (DOELU) v = v > 0.f ? v : expm1f(v);
        if (OUTBF)
            ((unsigned short*)outp)[(size_t)n * HCt + chb + j] = f2bf(v);
        else
            ((float*)outp)[(size_t)n * HCt + chb + j] = v;
    }
}

// --------------------------------------------------------------------------
extern "C" void kernel_launch(void* const* d_in, const int* in_sizes, int n_in,
                              void* d_out, int out_size, void* d_ws, size_t ws_size,
                              hipStream_t stream)
{
    const float* x   = (const float*)d_in[0];
    const int*   ei  = (const int*)d_in[1];
    const float* W1  = (const float*)d_in[2];
    const float* as1 = (const float*)d_in[3];
    const float* ad1 = (const float*)d_in[4];
    const float* b1  = (const float*)d_in[5];
    const float* W2  = (const float*)d_in[6];
    const float* as2 = (const float*)d_in[7];
    const float* ad2 = (const float*)d_in[8];
    const float* b2  = (const float*)d_in[9];
    const float* W3  = (const float*)d_in[10];
    const float* as3 = (const float*)d_in[11];
    const float* ad3 = (const float*)d_in[12];
    const float* b3  = (const float*)d_in[13];

    const int DIN = 256, HC = 512, DOUT = 64;
    int N = in_sizes[0] / DIN;
    int E = in_sizes[1] / 2;

    // workspace carve-up
    char* w = (char*)d_ws;
    auto alloc = [&](size_t bytes) -> char* {
        char* p = w;
        w += (bytes + 255) & ~(size_t)255;
        return p;
    };
    int* deg   = (int*)alloc((size_t)N * 4);
    int* cur   = (int*)alloc((size_t)N * 4);
    int* off   = (int*)alloc((size_t)(N + 1) * 4);
    int* csr   = (int*)alloc((size_t)(E + N) * 4);
    unsigned short* W1T = (unsigned short*)alloc((size_t)HC * DIN * 2);
    unsigned short* W2T = (unsigned short*)alloc((size_t)HC * HC * 2);
    unsigned short* W3T = (unsigned short*)alloc((size_t)DOUT * HC * 2);
    unsigned short* xb  = (unsigned short*)alloc((size_t)N * DIN * 2);  // bf16 GEMM A (layer1)
    unsigned short* act = (unsigned short*)alloc((size_t)N * HC * 2);   // bf16 activations
    unsigned short* hb  = (unsigned short*)alloc((size_t)N * HC * 2);   // bf16 h (layers 1-2)
    float* hbuf = (float*)alloc((size_t)N * DOUT * 4);                  // f32 h (layer 3)
    float* als  = (float*)alloc((size_t)N * 4 * 4);
    float* ald  = (float*)alloc((size_t)N * 4 * 4);

    // ---- CSR build ----
    k_initdeg<<<(N + 255) / 256, 256, 0, stream>>>(deg, N);
    k_hist<<<(E + 255) / 256, 256, 0, stream>>>(ei, E, deg);
    k_scan<<<1, 1024, 0, stream>>>(deg, off, cur, N);
    k_fill<<<(E + N + 255) / 256, 256, 0, stream>>>(ei, E, N, cur, csr);

    // ---- weight transposes + input conversion ----
    k_transpose<<<(DIN * HC + 255) / 256, 256, 0, stream>>>(W1, W1T, DIN, HC);
    k_transpose<<<(HC * HC + 255) / 256, 256, 0, stream>>>(W2, W2T, HC, HC);
    k_transpose<<<(HC * DOUT + 255) / 256, 256, 0, stream>>>(W3, W3T, HC, DOUT);
    k_cvt<<<(N * DIN + 255) / 256, 256, 0, stream>>>(x, xb, N * DIN);

    int tiles_m = (N + 63) / 64;
    auto gemm_blocks = [&](int tn) { return (tiles_m * tn + 3) / 4; };
    int nwave_blocks = (N + 3) / 4;

    // ---- layer 1 ----
    k_gemm<true><<<gemm_blocks(HC / 64), 256, 0, stream>>>(xb, W1T, hb, N, DIN, HC, HC / 64);
    k_al<512, 4, true><<<nwave_blocks, 256, 0, stream>>>(hb, as1, ad1, als, ald, N);
    k_aggr<512, 4, true, true, true><<<nwave_blocks, 256, 0, stream>>>(hb, als, ald, off, csr, b1, act, N);

    // ---- layer 2 ----
    k_gemm<true><<<gemm_blocks(HC / 64), 256, 0, stream>>>(act, W2T, hb, N, HC, HC, HC / 64);
    k_al<512, 4, true><<<nwave_blocks, 256, 0, stream>>>(hb, as2, ad2, als, ald, N);
    k_aggr<512, 4, true, true, true><<<nwave_blocks, 256, 0, stream>>>(hb, als, ald, off, csr, b2, act, N);

    // ---- layer 3 ----
    k_gemm<false><<<gemm_blocks(1), 256, 0, stream>>>(act, W3T, hbuf, N, HC, DOUT, 1);
    k_al<64, 1, false><<<nwave_blocks, 256, 0, stream>>>(hbuf, as3, ad3, als, ald, N);
    k_aggr<64, 1, false, false, false><<<nwave_blocks, 256, 0, stream>>>(
        hbuf, als, ald, off, csr, b3, d_out, N);
}

// Round 5
// 339.911 us; speedup vs baseline: 1.3255x; 1.1426x over previous
//
#include <hip/hip_runtime.h>

typedef short bf16x8 __attribute__((ext_vector_type(8)));
typedef float f32x4 __attribute__((ext_vector_type(4)));

__device__ __forceinline__ unsigned short f2bf(float f) {
    unsigned u = __float_as_uint(f);
    unsigned r = (u + 0x7fffu + ((u >> 16) & 1u)) >> 16;
    return (unsigned short)r;
}
__device__ __forceinline__ float bfu2f(unsigned short u) {
    return __uint_as_float(((unsigned)u) << 16);
}

// ---------------- CSR build ----------------
__global__ void k_hist(const int* __restrict__ ei, int E, int* deg) {
    int e = blockIdx.x * blockDim.x + threadIdx.x;
    if (e < E) atomicAdd(&deg[ei[E + e]], 1);
}
__global__ void k_scan(const int* __restrict__ deg, int* __restrict__ off,
                       int* __restrict__ cur, int N) {
    __shared__ int sums[1024];
    int t = threadIdx.x;
    int chunk = (N + 1023) >> 10;
    int lo = t * chunk;
    int hi = lo + chunk; if (hi > N) hi = N;
    if (lo > N) lo = N;
    int s = 0;
    for (int i = lo; i < hi; ++i) s += deg[i];
    sums[t] = s;
    __syncthreads();
    for (int dd = 1; dd < 1024; dd <<= 1) {
        int v = (t >= dd) ? sums[t - dd] : 0;
        __syncthreads();
        sums[t] += v;
        __syncthreads();
    }
    int run = sums[t] - s;  // exclusive prefix
    for (int i = lo; i < hi; ++i) { off[i] = run; cur[i] = run; run += deg[i]; }
    if (t == 1023) off[N] = run;
}
__global__ void k_fill(const int* __restrict__ ei, int E, int N,
                       int* cur, int* __restrict__ csr) {
    int i = blockIdx.x * blockDim.x + threadIdx.x;
    if (i < E) {
        int s = ei[i], d = ei[E + i];
        int pos = atomicAdd(&cur[d], 1);
        csr[pos] = s;
    } else if (i < E + N) {
        int nn = i - E;
        int pos = atomicAdd(&cur[nn], 1);
        csr[pos] = nn;
    }
}

// ---------------- fused prep: W transposes (f32->bf16), x cvt, deg init ----
__global__ void k_prep(const float* __restrict__ W1, unsigned short* __restrict__ W1T,
                       const float* __restrict__ W2, unsigned short* __restrict__ W2T,
                       const float* __restrict__ W3, unsigned short* __restrict__ W3T,
                       const float* __restrict__ x, unsigned short* __restrict__ xb,
                       int* __restrict__ deg,
                       int DIN, int HC, int DOUT, int N)
{
    int i = blockIdx.x * blockDim.x + threadIdx.x;
    int n1 = DIN * HC;            // W1: [DIN,HC] -> [HC,DIN]
    int n2 = n1 + HC * HC;
    int n3 = n2 + HC * DOUT;
    int n4 = n3 + N * DIN;
    int n5 = n4 + N;
    if (i < n1) {
        int k = i / HC, n = i - k * HC;
        W1T[n * DIN + k] = f2bf(W1[i]);
    } else if (i < n2) {
        int j = i - n1;
        int k = j / HC, n = j - k * HC;
        W2T[n * HC + k] = f2bf(W2[j]);
    } else if (i < n3) {
        int j = i - n2;
        int k = j / DOUT, n = j - k * DOUT;
        W3T[n * HC + k] = f2bf(W3[j]);
    } else if (i < n4) {
        int j = i - n3;
        xb[j] = f2bf(x[j]);
    } else if (i < n5) {
        deg[i - n4] = 1;  // self-loop
    }
}

// ---------------- GEMM: D[M,Nc] = A[M,K] (bf16) @ BT[Nc,K]^T (bf16) ----
// one wave computes a 64x64 tile; register double-buffered K loop
template <bool OUTBF>
__global__ __launch_bounds__(256) void k_gemm(
    const unsigned short* __restrict__ A, const unsigned short* __restrict__ BT,
    void* __restrict__ D, int M, int K, int Nc, int tiles_n)
{
    int wid = blockIdx.x * (blockDim.x >> 6) + (threadIdx.x >> 6);
    int tiles_m = (M + 63) >> 6;
    if (wid >= tiles_m * tiles_n) return;
    int lane = threadIdx.x & 63;
    int tm = wid / tiles_n, tn = wid - tm * tiles_n;
    int m0 = tm << 6, n0 = tn << 6;
    int r = lane & 15, q = lane >> 4;

    const unsigned short* Arow[4];
    const unsigned short* Brow[4];
#pragma unroll
    for (int i = 0; i < 4; ++i) {
        int row = m0 + 16 * i + r; row = row < M ? row : M - 1;
        Arow[i] = A + (size_t)row * K + q * 8;
        Brow[i] = BT + (size_t)(n0 + 16 * i + r) * K + q * 8;
    }

    f32x4 acc[4][4] = {};
    bf16x8 a[4], b[4], a2[4], b2[4];
#pragma unroll
    for (int i = 0; i < 4; ++i) {
        a[i] = *(const bf16x8*)(Arow[i]);
        b[i] = *(const bf16x8*)(Brow[i]);
    }
    for (int k0 = 0; k0 < K; k0 += 32) {
        int kn = k0 + 32;
        if (kn < K) {
#pragma unroll
            for (int i = 0; i < 4; ++i) {
                a2[i] = *(const bf16x8*)(Arow[i] + kn);
                b2[i] = *(const bf16x8*)(Brow[i] + kn);
            }
        }
#pragma unroll
        for (int i = 0; i < 4; ++i)
#pragma unroll
            for (int j = 0; j < 4; ++j)
                acc[i][j] = __builtin_amdgcn_mfma_f32_16x16x32_bf16(a[i], b[j], acc[i][j], 0, 0, 0);
        if (kn < K) {
#pragma unroll
            for (int i = 0; i < 4; ++i) { a[i] = a2[i]; b[i] = b2[i]; }
        }
    }
#pragma unroll
    for (int i = 0; i < 4; ++i) {
        int rowb = m0 + 16 * i + q * 4;
#pragma unroll
        for (int rr = 0; rr < 4; ++rr) {
            int row = rowb + rr;
            if (row < M) {
#pragma unroll
                for (int j = 0; j < 4; ++j) {
                    int col = n0 + 16 * j + r;
                    if (OUTBF)
                        ((unsigned short*)D)[(size_t)row * Nc + col] = f2bf(acc[i][j][rr]);
                    else
                        ((float*)D)[(size_t)row * Nc + col] = acc[i][j][rr];
                }
            }
        }
    }
}

// ---------------- attention logits per node: al_s, al_d -------------------
template <int HCt, int Ht, bool INBF>
__global__ __launch_bounds__(256) void k_al(
    const void* __restrict__ h, const float* __restrict__ asrc,
    const float* __restrict__ adst,
    float* __restrict__ als, float* __restrict__ ald, int N)
{
    int wid = blockIdx.x * (blockDim.x >> 6) + (threadIdx.x >> 6);
    if (wid >= N) return;
    int lane = threadIdx.x & 63;
    const int CH = HCt / 64;
    const int Gs = 64 / Ht;  // lanes per head
    float s = 0.f, d = 0.f;
    if constexpr (INBF) {
        // CH == 8: one 16B load of 8 bf16
        const uint4* hr = (const uint4*)((const unsigned short*)h + (size_t)wid * HCt) + lane;
        uint4 hv = *hr;
        unsigned wds[4] = {hv.x, hv.y, hv.z, hv.w};
        const f32x4* as4 = (const f32x4*)(asrc + lane * 8);
        const f32x4* ad4 = (const f32x4*)(adst + lane * 8);
        f32x4 av0 = as4[0], av1 = as4[1], dv0 = ad4[0], dv1 = ad4[1];
        float hf[8];
#pragma unroll
        for (int wv = 0; wv < 4; ++wv) {
            hf[2 * wv]     = __uint_as_float(wds[wv] << 16);
            hf[2 * wv + 1] = __uint_as_float(wds[wv] & 0xffff0000u);
        }
#pragma unroll
        for (int j = 0; j < 4; ++j) {
            s += hf[j] * av0[j] + hf[4 + j] * av1[j];
            d += hf[j] * dv0[j] + hf[4 + j] * dv1[j];
        }
    } else {
        const float* hr = (const float*)h + (size_t)wid * HCt + lane * CH;
#pragma unroll
        for (int j = 0; j < CH; ++j) {
            float hv = hr[j];
            int ch = lane * CH + j;
            s += hv * asrc[ch];
            d += hv * adst[ch];
        }
    }
#pragma unroll
    for (int dd = 1; dd < Gs; dd <<= 1) {
        s += __shfl_xor(s, dd);
        d += __shfl_xor(d, dd);
    }
    if ((lane & (Gs - 1)) == 0) {
        int hh = lane / Gs;
        als[wid * Ht + hh] = s;
        ald[wid * Ht + hh] = d;
    }
}

// ---------------- softmax over in-edges + aggregate -----------------------
// one wave per dst node; 4 edge-groups x 16 lanes; lane owns CH=HCt/16 channels
template <int HCt, int Ht, bool DOELU, bool OUTBF, bool INBF>
__global__ __launch_bounds__(256) void k_aggr(
    const void* __restrict__ h, const float* __restrict__ als,
    const float* __restrict__ aldv, const int* __restrict__ off,
    const int* __restrict__ csr, const float* __restrict__ bias,
    void* __restrict__ outp, int N)
{
    int n = blockIdx.x * (blockDim.x >> 6) + (threadIdx.x >> 6);
    if (n >= N) return;
    int lane = threadIdx.x & 63;
    int g = lane >> 4;        // edge group 0..3
    int p = lane & 15;        // channel-lane within group
    const int CH = HCt / 16;  // channels per lane (bf16:32, f32:4)
    const int C = HCt / Ht;
    const int HQ = INBF ? CH / 8 : CH / 4;  // 16B quads per lane row-slice
    int s0 = off[n], s1 = off[n + 1];

    float aldr[Ht];
#pragma unroll
    for (int hh = 0; hh < Ht; ++hh) aldr[hh] = aldv[n * Ht + hh];

    // pass 1: per-head max over in-edges (all 64 lanes stride edges)
    float mx[Ht];
#pragma unroll
    for (int hh = 0; hh < Ht; ++hh) mx[hh] = -3.4e38f;
    for (int t = s0 + lane; t < s1; t += 64) {
        int src = csr[t];
#pragma unroll
        for (int hh = 0; hh < Ht; ++hh) {
            float l = als[src * Ht + hh] + aldr[hh];
            l = l > 0.f ? l : 0.2f * l;
            mx[hh] = fmaxf(mx[hh], l);
        }
    }
#pragma unroll
    for (int dd = 1; dd < 64; dd <<= 1)
#pragma unroll
        for (int hh = 0; hh < Ht; ++hh)
            mx[hh] = fmaxf(mx[hh], __shfl_xor(mx[hh], dd));

    int myhead = (p * CH) / C;
    float mh = mx[0], aldh = aldr[0];
#pragma unroll
    for (int hh = 1; hh < Ht; ++hh)
        if (hh == myhead) { mh = mx[hh]; aldh = aldr[hh]; }

    // pass 2: 4 edges in flight (one per group), depth-2 software pipeline
    float acc[CH];
#pragma unroll
    for (int j = 0; j < CH; ++j) acc[j] = 0.f;
    float den = 0.f;

    auto stage = [&](int t, float& ex, uint4* hq) {
        int src = csr[t];
        float l = als[src * Ht + myhead] + aldh;
        l = l > 0.f ? l : 0.2f * l;
        ex = __expf(l - mh);
        if constexpr (INBF) {
            const uint4* row = (const uint4*)((const unsigned short*)h + (size_t)src * HCt) + p * HQ;
#pragma unroll
            for (int qq = 0; qq < HQ; ++qq) hq[qq] = row[qq];
        } else {
            const uint4* row = (const uint4*)((const float*)h + (size_t)src * HCt) + p * HQ;
#pragma unroll
            for (int qq = 0; qq < HQ; ++qq) hq[qq] = row[qq];
        }
    };

    int t = s0 + g;
    float ex; uint4 hq[HQ];
    bool have = t < s1;
    if (have) stage(t, ex, hq);
    while (have) {
        int tn = t + 4;
        float ex2; uint4 hq2[HQ];
        bool have2 = tn < s1;
        if (have2) stage(tn, ex2, hq2);
        // consume current stage
        den += ex;
        if constexpr (INBF) {
#pragma unroll
            for (int qq = 0; qq < HQ; ++qq) {
                unsigned wds[4] = {hq[qq].x, hq[qq].y, hq[qq].z, hq[qq].w};
#pragma unroll
                for (int wv = 0; wv < 4; ++wv) {
                    acc[qq * 8 + 2 * wv]     += ex * __uint_as_float(wds[wv] << 16);
                    acc[qq * 8 + 2 * wv + 1] += ex * __uint_as_float(wds[wv] & 0xffff0000u);
                }
            }
        } else {
#pragma unroll
            for (int qq = 0; qq < HQ; ++qq) {
                acc[qq * 4 + 0] += ex * __uint_as_float(hq[qq].x);
                acc[qq * 4 + 1] += ex * __uint_as_float(hq[qq].y);
                acc[qq * 4 + 2] += ex * __uint_as_float(hq[qq].z);
                acc[qq * 4 + 3] += ex * __uint_as_float(hq[qq].w);
            }
        }
        t = tn; have = have2; ex = ex2;
#pragma unroll
        for (int qq = 0; qq < HQ; ++qq) hq[qq] = hq2[qq];
    }

    // reduce across the 4 edge groups (lanes p, p+16, p+32, p+48)
    den += __shfl_xor(den, 16);
    den += __shfl_xor(den, 32);
#pragma unroll
    for (int j = 0; j < CH; ++j) {
        acc[j] += __shfl_xor(acc[j], 16);
        acc[j] += __shfl_xor(acc[j], 32);
    }
    float inv = 1.f / den;

    if constexpr (OUTBF) {
        // all 64 lanes write 16B: lane (g,p) writes channels p*CH + g*8 .. +8
        int cb = p * CH + g * 8;
        uint4 o;
        unsigned ww[4];
#pragma unroll
        for (int wv = 0; wv < 4; ++wv) {
            float v0 = acc[g * 8 + 2 * wv] * inv + bias[cb + 2 * wv];
            float v1 = acc[g * 8 + 2 * wv + 1] * inv + bias[cb + 2 * wv + 1];
            if (DOELU) {
                v0 = v0 > 0.f ? v0 : expm1f(v0);
                v1 = v1 > 0.f ? v1 : expm1f(v1);
            }
            ww[wv] = (unsigned)f2bf(v0) | ((unsigned)f2bf(v1) << 16);
        }
        o.x = ww[0]; o.y = ww[1]; o.z = ww[2]; o.w = ww[3];
        *((uint4*)((unsigned short*)outp + (size_t)n * HCt + cb)) = o;
    } else {
        // f32 out (HCt=64, CH=4): group 0 writes 16B per lane
        if (g == 0) {
            f32x4 o;
#pragma unroll
            for (int j = 0; j < 4; ++j) {
                float v = acc[j] * inv + bias[p * 4 + j];
                if (DOELU) v = v > 0.f ? v : expm1f(v);
                o[j] = v;
            }
            *((f32x4*)((float*)outp + (size_t)n * HCt + p * 4)) = o;
        }
    }
}

// --------------------------------------------------------------------------
extern "C" void kernel_launch(void* const* d_in, const int* in_sizes, int n_in,
                              void* d_out, int out_size, void* d_ws, size_t ws_size,
                              hipStream_t stream)
{
    const float* x   = (const float*)d_in[0];
    const int*   ei  = (const int*)d_in[1];
    const float* W1  = (const float*)d_in[2];
    const float* as1 = (const float*)d_in[3];
    const float* ad1 = (const float*)d_in[4];
    const float* b1  = (const float*)d_in[5];
    const float* W2  = (const float*)d_in[6];
    const float* as2 = (const float*)d_in[7];
    const float* ad2 = (const float*)d_in[8];
    const float* b2  = (const float*)d_in[9];
    const float* W3  = (const float*)d_in[10];
    const float* as3 = (const float*)d_in[11];
    const float* ad3 = (const float*)d_in[12];
    const float* b3  = (const float*)d_in[13];

    const int DIN = 256, HC = 512, DOUT = 64;
    int N = in_sizes[0] / DIN;
    int E = in_sizes[1] / 2;

    // workspace carve-up
    char* w = (char*)d_ws;
    auto alloc = [&](size_t bytes) -> char* {
        char* p = w;
        w += (bytes + 255) & ~(size_t)255;
        return p;
    };
    int* deg   = (int*)alloc((size_t)N * 4);
    int* cur   = (int*)alloc((size_t)N * 4);
    int* off   = (int*)alloc((size_t)(N + 1) * 4);
    int* csr   = (int*)alloc((size_t)(E + N) * 4);
    unsigned short* W1T = (unsigned short*)alloc((size_t)HC * DIN * 2);
    unsigned short* W2T = (unsigned short*)alloc((size_t)HC * HC * 2);
    unsigned short* W3T = (unsigned short*)alloc((size_t)DOUT * HC * 2);
    unsigned short* xb  = (unsigned short*)alloc((size_t)N * DIN * 2);  // bf16 GEMM A (layer1)
    unsigned short* act = (unsigned short*)alloc((size_t)N * HC * 2);   // bf16 activations
    unsigned short* hb  = (unsigned short*)alloc((size_t)N * HC * 2);   // bf16 h (layers 1-2)
    float* hbuf = (float*)alloc((size_t)N * DOUT * 4);                  // f32 h (layer 3)
    float* als  = (float*)alloc((size_t)N * 4 * 4);
    float* ald  = (float*)alloc((size_t)N * 4 * 4);

    // ---- prep (transposes + cvt + deg init), then CSR ----
    int prep_total = DIN * HC + HC * HC + HC * DOUT + N * DIN + N;
    k_prep<<<(prep_total + 255) / 256, 256, 0, stream>>>(
        W1, W1T, W2, W2T, W3, W3T, x, xb, deg, DIN, HC, DOUT, N);
    k_hist<<<(E + 255) / 256, 256, 0, stream>>>(ei, E, deg);
    k_scan<<<1, 1024, 0, stream>>>(deg, off, cur, N);
    k_fill<<<(E + N + 255) / 256, 256, 0, stream>>>(ei, E, N, cur, csr);

    int tiles_m = (N + 63) / 64;
    auto gemm_blocks = [&](int tn) { return (tiles_m * tn + 3) / 4; };
    int nwave_blocks = (N + 3) / 4;

    // ---- layer 1 ----
    k_gemm<true><<<gemm_blocks(HC / 64), 256, 0, stream>>>(xb, W1T, hb, N, DIN, HC, HC / 64);
    k_al<512, 4, true><<<nwave_blocks, 256, 0, stream>>>(hb, as1, ad1, als, ald, N);
    k_aggr<512, 4, true, true, true><<<nwave_blocks, 256, 0, stream>>>(hb, als, ald, off, csr, b1, act, N);

    // ---- layer 2 ----
    k_gemm<true><<<gemm_blocks(HC / 64), 256, 0, stream>>>(act, W2T, hb, N, HC, HC, HC / 64);
    k_al<512, 4, true><<<nwave_blocks, 256, 0, stream>>>(hb, as2, ad2, als, ald, N);
    k_aggr<512, 4, true, true, true><<<nwave_blocks, 256, 0, stream>>>(hb, als, ald, off, csr, b2, act, N);

    // ---- layer 3 ----
    k_gemm<false><<<gemm_blocks(1), 256, 0, stream>>>(act, W3T, hbuf, N, HC, DOUT, 1);
    k_al<64, 1, false><<<nwave_blocks, 256, 0, stream>>>(hbuf, as3, ad3, als, ald, N);
    k_aggr<64, 1, false, false, false><<<nwave_blocks, 256, 0, stream>>>(
        hbuf, als, ald, off, csr, b3, d_out, N);
}